// Round 14
// baseline (161.123 us; speedup 1.0000x reference)
//
#include <hip/hip_runtime.h>
#include <hip/hip_bf16.h>
#include <cstdint>
#include <cstddef>

#define NQH 16
#define NKH 4
#define HN 128
#define QBLK 64                      // rows per tile (2 waves x 32 rows x 2 groups)
#define KBLK 32
#define QSCALE 0.12751589542585458f  // (1/sqrt(128)) * log2(e)

typedef __bf16 bf16x8 __attribute__((ext_vector_type(8)));
typedef float f32x4 __attribute__((ext_vector_type(4)));

__device__ __forceinline__ void gload16(const void* g, void* l) {
  __builtin_amdgcn_global_load_lds(
      (const __attribute__((address_space(1))) void*)g,
      (__attribute__((address_space(3))) void*)l, 16, 0, 0);
}

// ---- pre-kernel A: K f32 [T][4][128] -> Kb bf16 [4][T][128] ----
__global__ __launch_bounds__(256) void cvt_k(const float* __restrict__ K,
                                             __bf16* __restrict__ Kb, int T) {
  const size_t idx8 = ((size_t)blockIdx.x * 256 + threadIdx.x) * 8;
  const int d = (int)(idx8 & 127);
  const int kvh = (int)((idx8 >> 7) & 3);
  const size_t t = idx8 >> 9;
  float4 a = *(const float4*)&K[idx8];
  float4 b = *(const float4*)&K[idx8 + 4];
  bf16x8 f;
  f[0] = (__bf16)a.x; f[1] = (__bf16)a.y; f[2] = (__bf16)a.z; f[3] = (__bf16)a.w;
  f[4] = (__bf16)b.x; f[5] = (__bf16)b.y; f[6] = (__bf16)b.z; f[7] = (__bf16)b.w;
  *(bf16x8*)&Kb[(size_t)kvh * T * HN + t * HN + d] = f;
}

// ---- pre-kernel B: V f32 [T][4][128] -> Vb bf16 [4][128][T] (transposed) ----
__global__ __launch_bounds__(128) void cvt_v(const float* __restrict__ V,
                                             __bf16* __restrict__ Vb, int T) {
  const int d = threadIdx.x;
  const int t0 = blockIdx.x * 8;
  const int kvh = blockIdx.y;
  bf16x8 f;
#pragma unroll
  for (int i = 0; i < 8; ++i)
    f[i] = (__bf16)V[(size_t)(t0 + i) * (NKH * HN) + kvh * HN + d];
  *(bf16x8*)&Vb[(size_t)kvh * HN * T + (size_t)d * T + t0] = f;
}

// ---- one 32-key block: swapped MFMA, two q-row-sets share all K/V ds_reads ----
// sX[c][i] = S[q][kb + koff], koff = hi*8 + c*4 + i (c = 0,1).
template <bool MASKED>
__device__ __forceinline__ void attn_iter(
    const char* Kc, const char* Vc, const bf16x8 qfA[4], const bf16x8 qfB[4],
    int ln, int hi, int vslot, int limA, float& mA, float& lA, f32x4* accA,
    float& mB, float& lB, f32x4* accB) {
  f32x4 sA[2], sB[2];
#pragma unroll
  for (int c = 0; c < 2; ++c) {
    sA[c] = (f32x4){0.f, 0.f, 0.f, 0.f};
    sB[c] = (f32x4){0.f, 0.f, 0.f, 0.f};
  }
  __builtin_amdgcn_s_setprio(1);
#pragma unroll
  for (int kc = 0; kc < 4; ++kc) {
#pragma unroll
    for (int c = 0; c < 2; ++c) {
      const int row = c * 16 + ln;
      const bf16x8 kf =
          *(const bf16x8*)(Kc + row * 256 + (((kc * 4 + hi) ^ (ln & 7)) << 4));
      sA[c] = __builtin_amdgcn_mfma_f32_16x16x32_bf16(kf, qfA[kc], sA[c], 0, 0, 0);
      sB[c] = __builtin_amdgcn_mfma_f32_16x16x32_bf16(kf, qfB[kc], sB[c], 0, 0, 0);
    }
  }
  __builtin_amdgcn_s_setprio(0);

  if (MASKED) {
    const int limB = limA + 16;
#pragma unroll
    for (int c = 0; c < 2; ++c)
#pragma unroll
      for (int i = 0; i < 4; ++i) {
        const int koff = hi * 8 + c * 4 + i;
        sA[c][i] = (koff <= limA) ? sA[c][i] : -1e30f;
        sB[c][i] = (koff <= limB) ? sB[c][i] : -1e30f;
      }
  }

  float mmA = fmaxf(fmaxf(fmaxf(sA[0][0], sA[0][1]), fmaxf(sA[0][2], sA[0][3])),
                    fmaxf(fmaxf(sA[1][0], sA[1][1]), fmaxf(sA[1][2], sA[1][3])));
  float mmB = fmaxf(fmaxf(fmaxf(sB[0][0], sB[0][1]), fmaxf(sB[0][2], sB[0][3])),
                    fmaxf(fmaxf(sB[1][0], sB[1][1]), fmaxf(sB[1][2], sB[1][3])));
  mmA = fmaxf(mmA, __shfl_xor(mmA, 16));
  mmA = fmaxf(mmA, __shfl_xor(mmA, 32));
  mmB = fmaxf(mmB, __shfl_xor(mmB, 16));
  mmB = fmaxf(mmB, __shfl_xor(mmB, 32));

  if (__any((mmA > mA + 8.0f) | (mmB > mB + 8.0f))) {  // defer-max THR=8
    const float mnA = fmaxf(mA, mmA), mnB = fmaxf(mB, mmB);
    const float cA = exp2f(mA - mnA), cB = exp2f(mB - mnB);
    mA = mnA; mB = mnB;
    lA *= cA; lB *= cB;
#pragma unroll
    for (int dt = 0; dt < 8; ++dt) { accA[dt] *= cA; accB[dt] *= cB; }
  }

  float pA[2][4], pB[2][4];
  float psA = 0.f, psB = 0.f;
#pragma unroll
  for (int c = 0; c < 2; ++c)
#pragma unroll
    for (int i = 0; i < 4; ++i) {
      pA[c][i] = exp2f(sA[c][i] - mA); psA += pA[c][i];
      pB[c][i] = exp2f(sB[c][i] - mB); psB += pB[c][i];
    }
  psA += __shfl_xor(psA, 16); psA += __shfl_xor(psA, 32);
  psB += __shfl_xor(psB, 16); psB += __shfl_xor(psB, 32);
  lA += psA; lB += psB;

  bf16x8 paA, paB;  // pa[e] = p at key hi*8+e -> c = e>>2, i = e&3
#pragma unroll
  for (int e = 0; e < 8; ++e) {
    paA[e] = (__bf16)pA[e >> 2][e & 3];
    paB[e] = (__bf16)pB[e >> 2][e & 3];
  }

  __builtin_amdgcn_s_setprio(1);
#pragma unroll
  for (int dt = 0; dt < 8; ++dt) {
    const int vr = dt * 16 + ln;
    const bf16x8 vb = *(const bf16x8*)(Vc + vr * 64 + vslot);
    accA[dt] = __builtin_amdgcn_mfma_f32_16x16x32_bf16(vb, paA, accA[dt], 0, 0, 0);
    accB[dt] = __builtin_amdgcn_mfma_f32_16x16x32_bf16(vb, paB, accB[dt], 0, 0, 0);
  }
  __builtin_amdgcn_s_setprio(0);
}

// ---- main: 4 waves = 2 K-chunk groups x (2 waves x 32 rows); 33 KB LDS ----
// snake rank: co-resident blocks on a CU get complementary depths
__global__ __launch_bounds__(256, 4) void attn_mfma10(
    const float* __restrict__ Q, const __bf16* __restrict__ Kb,
    const __bf16* __restrict__ Vb, const int* __restrict__ cu,
    float* __restrict__ O, int T, int nseg) {
  const int tid = threadIdx.x;
  const int w = tid >> 6, lane = tid & 63;
  const int g = w >> 1, wv = w & 1;
  const int ln = lane & 15, hi = lane >> 4;

  const int bid = blockIdx.x;
  const int round = bid >> 8, pos = bid & 255;
  const int rr = (round & 1) ? ((round << 8) | (255 - pos)) : bid;
  const int h = rr & 15;
  const int my_rank = rr >> 4;               // tile depth-rank (0 = deepest)
  const int kvh = h >> 2;

  __shared__ __align__(16) char smem[33296];
  // [0,16384): K tiles (2 groups x 8 KB)   [16384,32768): V tiles
  // [32768,33280): ml1[64][2]              [33280]: s_tile
  float* ml1 = (float*)(smem + 32768);
  int* s_tile = (int*)(smem + 33280);

  // ---- tile select: wave 0 ranks the 64 tiles by depth desc ----
  if (w == 0) {
    const int t2 = lane;
    const int r0t = t2 << 6;
    int st = 0;
    for (int s = 1; s < nseg; ++s) { const int c = cu[s]; if (c <= r0t) st = c; }
    const int dep = r0t + QBLK - st;
    int rk = 0;
    for (int j = 0; j < 64; ++j) {
      const int dj = __shfl(dep, j);
      rk += (dj > dep) || (dj == dep && j < t2);
    }
    if (rk == my_rank) *s_tile = t2;
  }
  __syncthreads();
  const int r0 = *s_tile << 6;

  int st0 = 0;
  for (int s = 1; s < nseg; ++s) { const int c = cu[s]; if (c <= r0) st0 = c; }
  const int kstart = st0;                    // 64-aligned
  const int n0 = (r0 + QBLK - kstart) >> 6;  // 32-key iters per group
  const int gbeg = kstart + g * n0 * KBLK;

  const __bf16* KbH = Kb + (size_t)kvh * T * HN;
  const __bf16* VbH = Vb + (size_t)kvh * HN * T;

  // ---- Q fragments: rows r0 + wv*32 + ln (set A), +16 (set B) ----
  bf16x8 qfA[4], qfB[4];
  {
    const float* qpA = &Q[(size_t)(r0 + wv * 32 + ln) * (NQH * HN) + h * HN];
    const float* qpB = qpA + (size_t)16 * (NQH * HN);
#pragma unroll
    for (int kc = 0; kc < 4; ++kc) {
      float4 a0 = *(const float4*)(qpA + kc * 32 + hi * 8);
      float4 a1 = *(const float4*)(qpA + kc * 32 + hi * 8 + 4);
      float4 b0 = *(const float4*)(qpB + kc * 32 + hi * 8);
      float4 b1 = *(const float4*)(qpB + kc * 32 + hi * 8 + 4);
      bf16x8 fa, fb;
      fa[0] = (__bf16)(a0.x * QSCALE); fa[1] = (__bf16)(a0.y * QSCALE);
      fa[2] = (__bf16)(a0.z * QSCALE); fa[3] = (__bf16)(a0.w * QSCALE);
      fa[4] = (__bf16)(a1.x * QSCALE); fa[5] = (__bf16)(a1.y * QSCALE);
      fa[6] = (__bf16)(a1.z * QSCALE); fa[7] = (__bf16)(a1.w * QSCALE);
      fb[0] = (__bf16)(b0.x * QSCALE); fb[1] = (__bf16)(b0.y * QSCALE);
      fb[2] = (__bf16)(b0.z * QSCALE); fb[3] = (__bf16)(b0.w * QSCALE);
      fb[4] = (__bf16)(b1.x * QSCALE); fb[5] = (__bf16)(b1.y * QSCALE);
      fb[6] = (__bf16)(b1.z * QSCALE); fb[7] = (__bf16)(b1.w * QSCALE);
      qfA[kc] = fa; qfB[kc] = fb;
    }
  }

  float mA = 0.f, lA = 0.f, mB = 0.f, lB = 0.f;
  f32x4 accA[8], accB[8];
#pragma unroll
  for (int dt = 0; dt < 8; ++dt) {
    accA[dt] = (f32x4){0.f, 0.f, 0.f, 0.f};
    accB[dt] = (f32x4){0.f, 0.f, 0.f, 0.f};
  }

  // ---- staging invariants (128 lanes/group, 4 K + 4 V x 16B each) ----
  const int gl = wv * 64 + lane;             // 0..127 within group
  // K: dest row R = (gl>>4) + 8j, slot gl&15; row R holds key kb+sigma(R),
  //    sigma = (r>>2)*8 + c*4 + (r&3), r=R&15, c=R>>4
  const int Rb = gl >> 4, sK = gl & 15;
  int key_j[4];
#pragma unroll
  for (int j = 0; j < 4; ++j)
    key_j[j] = ((Rb >> 2) << 3) + (Rb & 3) + ((j & 1) << 4) + ((j >> 1) << 2);
  const int kcolE = ((sK ^ Rb) << 3);        // element offset in dims
  // V: dest row d = (gl>>2) + 32j, slot gl&3; slot s holds keys (s^swz(d))*8,
  //    swz(d) = (d&3)^((d>>2)&3)
  const int db = gl >> 2, sV = gl & 3;
  const int swz_d = (db & 3) ^ ((db >> 2) & 3);
  const int vkeyE = ((sV ^ swz_d) << 3);     // element offset in keys
  char* ldsK = smem + g * 8192 + (size_t)gl * 16;
  char* ldsV = smem + 16384 + g * 8192 + (size_t)gl * 16;
  // V read slot (per lane const): hi ^ swz(vr) with swz(vr)=(ln&3)^((ln>>2)&3)
  const int vslot = ((hi ^ (ln & 3) ^ ((ln >> 2) & 3)) << 4);

  const char* Kc = smem + g * 8192;
  const char* Vc = smem + 16384 + g * 8192;
  const int relA = wv * 32 + ln;

  for (int it = 0; it < n0; ++it) {
    const int kb = gbeg + it * KBLK;
#pragma unroll
    for (int j = 0; j < 4; ++j)
      gload16(KbH + (size_t)(kb + key_j[j]) * HN + kcolE, ldsK + j * 2048);
#pragma unroll
    for (int j = 0; j < 4; ++j)
      gload16(VbH + (size_t)(db + 32 * j) * T + kb + vkeyE, ldsV + j * 2048);
    __syncthreads();  // drain DMA; tiles ready
    if (kb >= r0)
      attn_iter<true>(Kc, Vc, qfA, qfB, ln, hi, vslot, relA - (kb - r0), mA,
                      lA, accA, mB, lB, accB);
    else
      attn_iter<false>(Kc, Vc, qfA, qfB, ln, hi, vslot, 0, mA, lA, accA, mB,
                       lB, accB);
    __syncthreads();  // LDS reuse guard
  }

  // ---- local split-K merge via LDS (group1 -> group0) ----
  float* accf = (float*)smem;                // 64 x 128 f32 = 32 KB overlay
  if (g == 1) {
    if (hi == 0) {
      ml1[relA * 2] = mA;            ml1[relA * 2 + 1] = lA;
      ml1[(relA + 16) * 2] = mB;     ml1[(relA + 16) * 2 + 1] = lB;
    }
#pragma unroll
    for (int dt = 0; dt < 8; ++dt) {
      *(f32x4*)&accf[relA * 128 + ((dt ^ (relA & 7)) << 4) + (hi << 2)] = accA[dt];
      *(f32x4*)&accf[(relA + 16) * 128 + ((dt ^ ((relA + 16) & 7)) << 4) + (hi << 2)] = accB[dt];
    }
  }
  __syncthreads();
  if (g == 0) {
#pragma unroll
    for (int set = 0; set < 2; ++set) {
      const int row = relA + set * 16;
      const float mg = set ? mB : mA;
      const float lg = set ? lB : lA;
      f32x4* acc = set ? accB : accA;
      const float m1 = ml1[row * 2], l1v = ml1[row * 2 + 1];
      float c0 = 1.f, c1 = 0.f, l = lg;
      if (l1v != 0.f) {
        const float m = fmaxf(mg, m1);
        c0 = exp2f(mg - m); c1 = exp2f(m1 - m);
        l = lg * c0 + l1v * c1;
      }
      const float inv = 1.0f / l;
      float* op = &O[(size_t)(r0 + row) * (NQH * HN) + h * HN];
#pragma unroll
      for (int dt = 0; dt < 8; ++dt) {
        const f32x4 a1 = *(const f32x4*)&accf[row * 128 + ((dt ^ (row & 7)) << 4) + (hi << 2)];
        const f32x4 res = (acc[dt] * c0 + a1 * c1) * inv;
        *(f32x4*)&op[dt * 16 + hi * 4] = res;
      }
    }
  }
}

extern "C" void kernel_launch(void* const* d_in, const int* in_sizes, int n_in,
                              void* d_out, int out_size, void* d_ws, size_t ws_size,
                              hipStream_t stream) {
  const float* Q = (const float*)d_in[0];
  const float* K = (const float*)d_in[1];
  const float* V = (const float*)d_in[2];
  const int* cu = (const int*)d_in[3];
  float* O = (float*)d_out;

  const int T = in_sizes[0] / (NQH * HN);  // 4096
  const int nseg = in_sizes[3] - 1;        // 4

  const size_t need = (size_t)2 * NKH * T * HN * sizeof(__bf16);  // 8 MB
  if (ws_size < need) return;

  __bf16* Kb = (__bf16*)d_ws;
  __bf16* Vb = (__bf16*)d_ws + (size_t)NKH * T * HN;

  const int nelem = T * NKH * HN;
  cvt_k<<<nelem / 8 / 256, 256, 0, stream>>>(K, Kb, T);
  cvt_v<<<dim3(T / 8, NKH), 128, 0, stream>>>(V, Vb, T);

  // 64 tiles x 16 heads; snake-ordered depth ranks
  attn_mfma10<<<1024, 256, 0, stream>>>(Q, Kb, Vb, cu, O, T, nseg);
}

// Round 15
// 72.406 us; speedup vs baseline: 2.2253x; 2.2253x over previous
//
#include <hip/hip_runtime.h>
#include <hip/hip_bf16.h>
#include <cstdint>
#include <cstddef>

#define NQH 16
#define NKH 4
#define HN 128
#define QBLK 64                      // rows per tile (2 waves x 32 rows x 2 groups)
#define KBLK 32
#define QSCALE 0.12751589542585458f  // (1/sqrt(128)) * log2(e)

typedef __bf16 bf16x8 __attribute__((ext_vector_type(8)));
typedef float f32x4 __attribute__((ext_vector_type(4)));

__device__ __forceinline__ void gload16(const void* g, void* l) {
  __builtin_amdgcn_global_load_lds(
      (const __attribute__((address_space(1))) void*)g,
      (__attribute__((address_space(3))) void*)l, 16, 0, 0);
}

// ---- pre-kernel A: K f32 [T][4][128] -> Kb bf16 [4][T][128] ----
__global__ __launch_bounds__(256) void cvt_k(const float* __restrict__ K,
                                             __bf16* __restrict__ Kb, int T) {
  const size_t idx8 = ((size_t)blockIdx.x * 256 + threadIdx.x) * 8;
  const int d = (int)(idx8 & 127);
  const int kvh = (int)((idx8 >> 7) & 3);
  const size_t t = idx8 >> 9;
  float4 a = *(const float4*)&K[idx8];
  float4 b = *(const float4*)&K[idx8 + 4];
  bf16x8 f;
  f[0] = (__bf16)a.x; f[1] = (__bf16)a.y; f[2] = (__bf16)a.z; f[3] = (__bf16)a.w;
  f[4] = (__bf16)b.x; f[5] = (__bf16)b.y; f[6] = (__bf16)b.z; f[7] = (__bf16)b.w;
  *(bf16x8*)&Kb[(size_t)kvh * T * HN + t * HN + d] = f;
}

// ---- pre-kernel B: V f32 [T][4][128] -> Vb bf16 [4][128][T] (transposed) ----
__global__ __launch_bounds__(128) void cvt_v(const float* __restrict__ V,
                                             __bf16* __restrict__ Vb, int T) {
  const int d = threadIdx.x;
  const int t0 = blockIdx.x * 8;
  const int kvh = blockIdx.y;
  bf16x8 f;
#pragma unroll
  for (int i = 0; i < 8; ++i)
    f[i] = (__bf16)V[(size_t)(t0 + i) * (NKH * HN) + kvh * HN + d];
  *(bf16x8*)&Vb[(size_t)kvh * HN * T + (size_t)d * T + t0] = f;
}

// ---- one 32-key block: swapped MFMA, two q-row-sets share all K/V ds_reads ----
// sX[c][i] = S[q][kb + koff], koff = hi*8 + c*4 + i (c = 0,1).
template <bool MASKED>
__device__ __forceinline__ void attn_iter(
    const char* Kc, const char* Vc, const bf16x8 qfA[4], const bf16x8 qfB[4],
    int ln, int hi, int vslot, int limA, float& mA, float& lA, f32x4* accA,
    float& mB, float& lB, f32x4* accB) {
  f32x4 sA[2], sB[2];
#pragma unroll
  for (int c = 0; c < 2; ++c) {
    sA[c] = (f32x4){0.f, 0.f, 0.f, 0.f};
    sB[c] = (f32x4){0.f, 0.f, 0.f, 0.f};
  }
  __builtin_amdgcn_s_setprio(1);
#pragma unroll
  for (int kc = 0; kc < 4; ++kc) {
#pragma unroll
    for (int c = 0; c < 2; ++c) {
      const int row = c * 16 + ln;
      const bf16x8 kf =
          *(const bf16x8*)(Kc + row * 256 + (((kc * 4 + hi) ^ (ln & 7)) << 4));
      sA[c] = __builtin_amdgcn_mfma_f32_16x16x32_bf16(kf, qfA[kc], sA[c], 0, 0, 0);
      sB[c] = __builtin_amdgcn_mfma_f32_16x16x32_bf16(kf, qfB[kc], sB[c], 0, 0, 0);
    }
  }
  __builtin_amdgcn_s_setprio(0);

  if (MASKED) {
    const int limB = limA + 16;
#pragma unroll
    for (int c = 0; c < 2; ++c)
#pragma unroll
      for (int i = 0; i < 4; ++i) {
        const int koff = hi * 8 + c * 4 + i;
        sA[c][i] = (koff <= limA) ? sA[c][i] : -1e30f;
        sB[c][i] = (koff <= limB) ? sB[c][i] : -1e30f;
      }
  }

  float mmA = fmaxf(fmaxf(fmaxf(sA[0][0], sA[0][1]), fmaxf(sA[0][2], sA[0][3])),
                    fmaxf(fmaxf(sA[1][0], sA[1][1]), fmaxf(sA[1][2], sA[1][3])));
  float mmB = fmaxf(fmaxf(fmaxf(sB[0][0], sB[0][1]), fmaxf(sB[0][2], sB[0][3])),
                    fmaxf(fmaxf(sB[1][0], sB[1][1]), fmaxf(sB[1][2], sB[1][3])));
  mmA = fmaxf(mmA, __shfl_xor(mmA, 16));
  mmA = fmaxf(mmA, __shfl_xor(mmA, 32));
  mmB = fmaxf(mmB, __shfl_xor(mmB, 16));
  mmB = fmaxf(mmB, __shfl_xor(mmB, 32));

  if (__any((mmA > mA + 8.0f) | (mmB > mB + 8.0f))) {  // defer-max THR=8
    const float mnA = fmaxf(mA, mmA), mnB = fmaxf(mB, mmB);
    const float cA = exp2f(mA - mnA), cB = exp2f(mB - mnB);
    mA = mnA; mB = mnB;
    lA *= cA; lB *= cB;
#pragma unroll
    for (int dt = 0; dt < 8; ++dt) { accA[dt] *= cA; accB[dt] *= cB; }
  }

  float pA[2][4], pB[2][4];
  float psA = 0.f, psB = 0.f;
#pragma unroll
  for (int c = 0; c < 2; ++c)
#pragma unroll
    for (int i = 0; i < 4; ++i) {
      pA[c][i] = exp2f(sA[c][i] - mA); psA += pA[c][i];
      pB[c][i] = exp2f(sB[c][i] - mB); psB += pB[c][i];
    }
  psA += __shfl_xor(psA, 16); psA += __shfl_xor(psA, 32);
  psB += __shfl_xor(psB, 16); psB += __shfl_xor(psB, 32);
  lA += psA; lB += psB;

  bf16x8 paA, paB;  // pa[e] = p at key hi*8+e -> c = e>>2, i = e&3
#pragma unroll
  for (int e = 0; e < 8; ++e) {
    paA[e] = (__bf16)pA[e >> 2][e & 3];
    paB[e] = (__bf16)pB[e >> 2][e & 3];
  }

  __builtin_amdgcn_s_setprio(1);
#pragma unroll
  for (int dt = 0; dt < 8; ++dt) {
    const int vr = dt * 16 + ln;
    const bf16x8 vb = *(const bf16x8*)(Vc + vr * 64 + vslot);
    accA[dt] = __builtin_amdgcn_mfma_f32_16x16x32_bf16(vb, paA, accA[dt], 0, 0, 0);
    accB[dt] = __builtin_amdgcn_mfma_f32_16x16x32_bf16(vb, paB, accB[dt], 0, 0, 0);
  }
  __builtin_amdgcn_s_setprio(0);
}

// ---- main: 4 waves = 2 K-chunk groups x (2 waves x 32 rows); 33 KB LDS ----
// snake rank: co-resident blocks on a CU get complementary depths
__global__ __launch_bounds__(256, 3) void attn_mfma10(
    const float* __restrict__ Q, const __bf16* __restrict__ Kb,
    const __bf16* __restrict__ Vb, const int* __restrict__ cu,
    float* __restrict__ O, int T, int nseg) {
  const int tid = threadIdx.x;
  const int w = tid >> 6, lane = tid & 63;
  const int g = w >> 1, wv = w & 1;
  const int ln = lane & 15, hi = lane >> 4;

  const int bid = blockIdx.x;
  const int round = bid >> 8, pos = bid & 255;
  const int rr = (round & 1) ? ((round << 8) | (255 - pos)) : bid;
  const int h = rr & 15;
  const int my_rank = rr >> 4;               // tile depth-rank (0 = deepest)
  const int kvh = h >> 2;

  __shared__ __align__(16) char smem[33296];
  // [0,16384): K tiles (2 groups x 8 KB)   [16384,32768): V tiles
  // [32768,33280): ml1[64][2]              [33280]: s_tile
  float* ml1 = (float*)(smem + 32768);
  int* s_tile = (int*)(smem + 33280);

  // ---- tile select: wave 0 ranks the 64 tiles by depth desc ----
  if (w == 0) {
    const int t2 = lane;
    const int r0t = t2 << 6;
    int st = 0;
    for (int s = 1; s < nseg; ++s) { const int c = cu[s]; if (c <= r0t) st = c; }
    const int dep = r0t + QBLK - st;
    int rk = 0;
    for (int j = 0; j < 64; ++j) {
      const int dj = __shfl(dep, j);
      rk += (dj > dep) || (dj == dep && j < t2);
    }
    if (rk == my_rank) *s_tile = t2;
  }
  __syncthreads();
  const int r0 = *s_tile << 6;

  int st0 = 0;
  for (int s = 1; s < nseg; ++s) { const int c = cu[s]; if (c <= r0) st0 = c; }
  const int kstart = st0;                    // 64-aligned
  const int n0 = (r0 + QBLK - kstart) >> 6;  // 32-key iters per group
  const int gbeg = kstart + g * n0 * KBLK;

  const __bf16* KbH = Kb + (size_t)kvh * T * HN;
  const __bf16* VbH = Vb + (size_t)kvh * HN * T;

  // ---- Q fragments: rows r0 + wv*32 + ln (set A), +16 (set B) ----
  bf16x8 qfA[4], qfB[4];
  {
    const float* qpA = &Q[(size_t)(r0 + wv * 32 + ln) * (NQH * HN) + h * HN];
    const float* qpB = qpA + (size_t)16 * (NQH * HN);
#pragma unroll
    for (int kc = 0; kc < 4; ++kc) {
      float4 a0 = *(const float4*)(qpA + kc * 32 + hi * 8);
      float4 a1 = *(const float4*)(qpA + kc * 32 + hi * 8 + 4);
      float4 b0 = *(const float4*)(qpB + kc * 32 + hi * 8);
      float4 b1 = *(const float4*)(qpB + kc * 32 + hi * 8 + 4);
      bf16x8 fa, fb;
      fa[0] = (__bf16)(a0.x * QSCALE); fa[1] = (__bf16)(a0.y * QSCALE);
      fa[2] = (__bf16)(a0.z * QSCALE); fa[3] = (__bf16)(a0.w * QSCALE);
      fa[4] = (__bf16)(a1.x * QSCALE); fa[5] = (__bf16)(a1.y * QSCALE);
      fa[6] = (__bf16)(a1.z * QSCALE); fa[7] = (__bf16)(a1.w * QSCALE);
      fb[0] = (__bf16)(b0.x * QSCALE); fb[1] = (__bf16)(b0.y * QSCALE);
      fb[2] = (__bf16)(b0.z * QSCALE); fb[3] = (__bf16)(b0.w * QSCALE);
      fb[4] = (__bf16)(b1.x * QSCALE); fb[5] = (__bf16)(b1.y * QSCALE);
      fb[6] = (__bf16)(b1.z * QSCALE); fb[7] = (__bf16)(b1.w * QSCALE);
      qfA[kc] = fa; qfB[kc] = fb;
    }
  }

  float mA = 0.f, lA = 0.f, mB = 0.f, lB = 0.f;
  f32x4 accA[8], accB[8];
#pragma unroll
  for (int dt = 0; dt < 8; ++dt) {
    accA[dt] = (f32x4){0.f, 0.f, 0.f, 0.f};
    accB[dt] = (f32x4){0.f, 0.f, 0.f, 0.f};
  }

  // ---- staging invariants (128 lanes/group, 4 K + 4 V x 16B each) ----
  const int gl = wv * 64 + lane;             // 0..127 within group
  // K: dest row R = (gl>>4) + 8j, slot gl&15; row R holds key kb+sigma(R),
  //    sigma = (r>>2)*8 + c*4 + (r&3), r=R&15, c=R>>4
  const int Rb = gl >> 4, sK = gl & 15;
  int key_j[4];
#pragma unroll
  for (int j = 0; j < 4; ++j)
    key_j[j] = ((Rb >> 2) << 3) + (Rb & 3) + ((j & 1) << 4) + ((j >> 1) << 2);
  const int kcolE = ((sK ^ Rb) << 3);        // element offset in dims
  // V: dest row d = (gl>>2) + 32j, slot gl&3; slot s holds keys (s^swz(d))*8,
  //    swz(d) = (d&3)^((d>>2)&3)
  const int db = gl >> 2, sV = gl & 3;
  const int swz_d = (db & 3) ^ ((db >> 2) & 3);
  const int vkeyE = ((sV ^ swz_d) << 3);     // element offset in keys
  char* ldsK = smem + g * 8192 + (size_t)gl * 16;
  char* ldsV = smem + 16384 + g * 8192 + (size_t)gl * 16;
  // V read slot (per lane const): hi ^ swz(vr) with swz(vr)=(ln&3)^((ln>>2)&3)
  const int vslot = ((hi ^ (ln & 3) ^ ((ln >> 2) & 3)) << 4);

  const char* Kc = smem + g * 8192;
  const char* Vc = smem + 16384 + g * 8192;
  const int relA = wv * 32 + ln;

  for (int it = 0; it < n0; ++it) {
    const int kb = gbeg + it * KBLK;
#pragma unroll
    for (int j = 0; j < 4; ++j)
      gload16(KbH + (size_t)(kb + key_j[j]) * HN + kcolE, ldsK + j * 2048);
#pragma unroll
    for (int j = 0; j < 4; ++j)
      gload16(VbH + (size_t)(db + 32 * j) * T + kb + vkeyE, ldsV + j * 2048);
    __syncthreads();  // drain DMA; tiles ready
    if (kb >= r0)
      attn_iter<true>(Kc, Vc, qfA, qfB, ln, hi, vslot, relA - (kb - r0), mA,
                      lA, accA, mB, lB, accB);
    else
      attn_iter<false>(Kc, Vc, qfA, qfB, ln, hi, vslot, 0, mA, lA, accA, mB,
                       lB, accB);
    __syncthreads();  // LDS reuse guard
  }

  // ---- local split-K merge via LDS (group1 -> group0) ----
  float* accf = (float*)smem;                // 64 x 128 f32 = 32 KB overlay
  if (g == 1) {
    if (hi == 0) {
      ml1[relA * 2] = mA;            ml1[relA * 2 + 1] = lA;
      ml1[(relA + 16) * 2] = mB;     ml1[(relA + 16) * 2 + 1] = lB;
    }
#pragma unroll
    for (int dt = 0; dt < 8; ++dt) {
      *(f32x4*)&accf[relA * 128 + ((dt ^ (relA & 7)) << 4) + (hi << 2)] = accA[dt];
      *(f32x4*)&accf[(relA + 16) * 128 + ((dt ^ ((relA + 16) & 7)) << 4) + (hi << 2)] = accB[dt];
    }
  }
  __syncthreads();
  if (g == 0) {
#pragma unroll
    for (int set = 0; set < 2; ++set) {
      const int row = relA + set * 16;
      const float mg = set ? mB : mA;
      const float lg = set ? lB : lA;
      f32x4* acc = set ? accB : accA;
      const float m1 = ml1[row * 2], l1v = ml1[row * 2 + 1];
      float c0 = 1.f, c1 = 0.f, l = lg;
      if (l1v != 0.f) {
        const float m = fmaxf(mg, m1);
        c0 = exp2f(mg - m); c1 = exp2f(m1 - m);
        l = lg * c0 + l1v * c1;
      }
      const float inv = 1.0f / l;
      float* op = &O[(size_t)(r0 + row) * (NQH * HN) + h * HN];
#pragma unroll
      for (int dt = 0; dt < 8; ++dt) {
        const f32x4 a1 = *(const f32x4*)&accf[row * 128 + ((dt ^ (row & 7)) << 4) + (hi << 2)];
        const f32x4 res = (acc[dt] * c0 + a1 * c1) * inv;
        *(f32x4*)&op[dt * 16 + hi * 4] = res;
      }
    }
  }
}

extern "C" void kernel_launch(void* const* d_in, const int* in_sizes, int n_in,
                              void* d_out, int out_size, void* d_ws, size_t ws_size,
                              hipStream_t stream) {
  const float* Q = (const float*)d_in[0];
  const float* K = (const float*)d_in[1];
  const float* V = (const float*)d_in[2];
  const int* cu = (const int*)d_in[3];
  float* O = (float*)d_out;

  const int T = in_sizes[0] / (NQH * HN);  // 4096
  const int nseg = in_sizes[3] - 1;        // 4

  const size_t need = (size_t)2 * NKH * T * HN * sizeof(__bf16);  // 8 MB
  if (ws_size < need) return;

  __bf16* Kb = (__bf16*)d_ws;
  __bf16* Vb = (__bf16*)d_ws + (size_t)NKH * T * HN;

  const int nelem = T * NKH * HN;
  cvt_k<<<nelem / 8 / 256, 256, 0, stream>>>(K, Kb, T);
  cvt_v<<<dim3(T / 8, NKH), 128, 0, stream>>>(V, Vb, T);

  // 64 tiles x 16 heads; snake-ordered depth ranks
  attn_mfma10<<<1024, 256, 0, stream>>>(Q, Kb, Vb, cu, O, T, nseg);
}